// Round 8
// baseline (2114.624 us; speedup 1.0000x reference)
//
#include <hip/hip_runtime.h>

#define N_NODES 100000
#define N_EDGES 1600000
#define T_STEPS 6
#define FDIM    64
#define SEG     (T_STEPS * N_NODES)
#define C2      0.01f

// Build per-(t,dst)-segment linked lists over edges. One atomicExch per edge
// on the 2.4MB head array (L2-resident).
__global__ __launch_bounds__(256) void k_build(
    const int* __restrict__ dst, const int* __restrict__ tix,
    int* __restrict__ head, int* __restrict__ nxt)
{
  const int e = blockIdx.x * blockDim.x + threadIdx.x;
  if (e >= N_EDGES) return;
  const int key = tix[e] * N_NODES + dst[e];
  nxt[e] = atomicExch(&head[key], e);
}

// One wave per NODE, lane = feature. Walk the node's 6 per-t edge lists
// concurrently (6 independent chains -> 6x MLP). Same list order as round 5
// -> sums/cnt bit-identical.
__global__ __launch_bounds__(256) void k_sum6(
    const float* __restrict__ feat, const int* __restrict__ src,
    const int* __restrict__ head, const int* __restrict__ nxt,
    float* __restrict__ sums, float* __restrict__ cnt)
{
  const int lane = threadIdx.x & 63;
  const int n = blockIdx.x * (blockDim.x >> 6) + (threadIdx.x >> 6);
  if (n >= N_NODES) return;

  int e0 = head[(size_t)0 * N_NODES + n];
  int e1 = head[(size_t)1 * N_NODES + n];
  int e2 = head[(size_t)2 * N_NODES + n];
  int e3 = head[(size_t)3 * N_NODES + n];
  int e4 = head[(size_t)4 * N_NODES + n];
  int e5 = head[(size_t)5 * N_NODES + n];

  float v0 = 0.f, v1 = 0.f, v2 = 0.f, v3 = 0.f, v4 = 0.f, v5 = 0.f;
  int c0 = 0, c1 = 0, c2 = 0, c3 = 0, c4 = 0, c5 = 0;

  while ((e0 >= 0) | (e1 >= 0) | (e2 >= 0) | (e3 >= 0) | (e4 >= 0) | (e5 >= 0)) {
    if (e0 >= 0) { v0 += feat[(size_t)src[e0] * FDIM + lane]; ++c0; e0 = nxt[e0]; }
    if (e1 >= 0) { v1 += feat[(size_t)src[e1] * FDIM + lane]; ++c1; e1 = nxt[e1]; }
    if (e2 >= 0) { v2 += feat[(size_t)src[e2] * FDIM + lane]; ++c2; e2 = nxt[e2]; }
    if (e3 >= 0) { v3 += feat[(size_t)src[e3] * FDIM + lane]; ++c3; e3 = nxt[e3]; }
    if (e4 >= 0) { v4 += feat[(size_t)src[e4] * FDIM + lane]; ++c4; e4 = nxt[e4]; }
    if (e5 >= 0) { v5 += feat[(size_t)src[e5] * FDIM + lane]; ++c5; e5 = nxt[e5]; }
  }

  sums[((size_t)0 * N_NODES + n) * FDIM + lane] = v0;
  sums[((size_t)1 * N_NODES + n) * FDIM + lane] = v1;
  sums[((size_t)2 * N_NODES + n) * FDIM + lane] = v2;
  sums[((size_t)3 * N_NODES + n) * FDIM + lane] = v3;
  sums[((size_t)4 * N_NODES + n) * FDIM + lane] = v4;
  sums[((size_t)5 * N_NODES + n) * FDIM + lane] = v5;
  if (lane == 0) {
    cnt[(size_t)0 * N_NODES + n] = (float)c0;
    cnt[(size_t)1 * N_NODES + n] = (float)c1;
    cnt[(size_t)2 * N_NODES + n] = (float)c2;
    cnt[(size_t)3 * N_NODES + n] = (float)c3;
    cnt[(size_t)4 * N_NODES + n] = (float)c4;
    cnt[(size_t)5 * N_NODES + n] = (float)c5;
  }
}

// Round-1 arithmetic, j-split via blockIdx.y (NOT threadIdx: round 7 proved
// a threadIdx-derived jb defeats uniformity analysis -> W loads became
// 64-lane vector loads of a uniform address, SGPR 112->32, 2.4x slower).
// jb = blockIdx.y*JBLK is block-uniform -> W/bias loads stay batched s_load,
// FMAs take W from SGPRs. Per-j fma chains and pass-A rounding are verbatim
// round 1 -> absmax unchanged. 2 node-group waves per 128-thread block.
template <int OUTF, int JBLK>
__global__ __launch_bounds__(128) void k_fused_gemm(
    const float* __restrict__ sums, const float* __restrict__ cnt,
    const float* __restrict__ W, const float* __restrict__ bias,
    float* __restrict__ out)
{
  const int lane = threadIdx.x & 63;
  const int grp = blockIdx.x * 2 + (threadIdx.x >> 6);
  const int jb  = blockIdx.y * JBLK;          // block-uniform j-slice

  int n = grp * 64 + lane;
  const bool valid = (n < N_NODES);
  if (!valid) n = N_NODES - 1;

  // ---- pass A: scale factors per t (verbatim round-1 arithmetic) ----
  float sc0, sc1, sc2, sc3, sc4, sc5;
  #pragma unroll
  for (int t = 0; t < T_STEPS; ++t) {
    const float c  = cnt[(size_t)t * N_NODES + n];
    const float rc = 1.0f / fmaxf(c, 1.0f);
    const float4* row = (const float4*)(sums + ((size_t)t * N_NODES + n) * FDIM);
    float ss = 0.0f;
    #pragma unroll 1
    for (int q = 0; q < FDIM / 4; ++q) {
      float4 v = row[q];
      float m0 = v.x * rc, m1 = v.y * rc, m2 = v.z * rc, m3 = v.w * rc;
      ss += m0 * m0 + m1 * m1 + m2 * m2 + m3 * m3;
    }
    const float norm = 1.0f - C2 * ss;
    const float s = rc / norm;
    if (t == 0) sc0 = s; else if (t == 1) sc1 = s; else if (t == 2) sc2 = s;
    else if (t == 3) sc3 = s; else if (t == 4) sc4 = s; else sc5 = s;
  }

  // ---- pass B: dense layer, j-slice [jb, jb+JBLK) ----
  float acc[JBLK];
  #pragma unroll
  for (int j = 0; j < JBLK; ++j) acc[j] = bias[jb + j];

  #pragma unroll 1
  for (int t = 0; t < T_STEPS; ++t) {
    const float s = (t == 0) ? sc0 : (t == 1) ? sc1 : (t == 2) ? sc2
                  : (t == 3) ? sc3 : (t == 4) ? sc4 : sc5;
    const float4* row = (const float4*)(sums + ((size_t)t * N_NODES + n) * FDIM);
    #pragma unroll 1
    for (int q8 = 0; q8 < FDIM / 8; ++q8) {
      const float4 a = row[q8 * 2 + 0];
      const float4 b4 = row[q8 * 2 + 1];
      const float hv[8] = {a.x, a.y, a.z, a.w, b4.x, b4.y, b4.z, b4.w};
      const float* wr = W + ((size_t)t * FDIM + q8 * 8) * OUTF + jb;
      #pragma unroll
      for (int i = 0; i < 8; ++i) {
        const float hs = hv[i] * s;
        #pragma unroll
        for (int j = 0; j < JBLK; ++j)
          acc[j] = fmaf(hs, wr[i * OUTF + j], acc[j]);
      }
    }
  }

  if (valid) {
    float* o = out + (size_t)n * OUTF + jb;
    #pragma unroll
    for (int j = 0; j < JBLK; ++j) o[j] = fmaxf(acc[j], 0.0f);
  }
}

extern "C" void kernel_launch(void* const* d_in, const int* in_sizes, int n_in,
                              void* d_out, int out_size, void* d_ws, size_t ws_size,
                              hipStream_t stream) {
  const float* x  = (const float*)d_in[0];
  const int*  ei  = (const int*)d_in[1];
  const int*  tix = (const int*)d_in[2];
  const float* W1 = (const float*)d_in[3];
  const float* b1 = (const float*)d_in[4];
  const float* W2 = (const float*)d_in[5];
  const float* b2 = (const float*)d_in[6];

  const int* src = ei;
  const int* dst = ei + N_EDGES;

  // Workspace: head[SEG] | nxt[NE] | sums[SEG*64] | cnt[SEG] | h1[NN*64]
  int*   head = (int*)d_ws;
  int*   nxt  = head + SEG;
  float* sums = (float*)(nxt + N_EDGES);
  float* cnt  = sums + (size_t)SEG * FDIM;
  float* h1   = cnt + SEG;

  const int node_grid = (N_NODES + 3) / 4;       // k_sum6: 4 waves/block
  const int ngrp = (N_NODES + 63) / 64;          // 1563 64-node groups
  const dim3 gemm_grid((ngrp + 1) / 2, 4);       // 2 groups/block x 4 j-slices

  hipMemsetAsync(head, 0xFF, (size_t)SEG * sizeof(int), stream);
  k_build<<<(N_EDGES + 255) / 256, 256, 0, stream>>>(dst, tix, head, nxt);

  // Layer 1
  k_sum6<<<node_grid, 256, 0, stream>>>(x, src, head, nxt, sums, cnt);
  k_fused_gemm<64, 16><<<gemm_grid, 128, 0, stream>>>(sums, cnt, W1, b1, h1);

  // Layer 2 (same edge lists; cnt identical but rewritten -- harmless)
  k_sum6<<<node_grid, 256, 0, stream>>>(h1, src, head, nxt, sums, cnt);
  k_fused_gemm<16, 4><<<gemm_grid, 128, 0, stream>>>(sums, cnt, W2, b2, (float*)d_out);
}

// Round 9
// 709.242 us; speedup vs baseline: 2.9815x; 2.9815x over previous
//
#include <hip/hip_runtime.h>

#define N_NODES 100000
#define N_EDGES 1600000
#define T_STEPS 6
#define FDIM    64
#define SEG     (T_STEPS * N_NODES)
#define C2      0.01f

// Build per-(t,dst)-segment linked lists over edges. One atomicExch per edge
// on the 2.4MB head array (L2-resident).
__global__ __launch_bounds__(256) void k_build(
    const int* __restrict__ dst, const int* __restrict__ tix,
    int* __restrict__ head, int* __restrict__ nxt)
{
  const int e = blockIdx.x * blockDim.x + threadIdx.x;
  if (e >= N_EDGES) return;
  const int key = tix[e] * N_NODES + dst[e];
  nxt[e] = atomicExch(&head[key], e);
}

// One wave per NODE, lane = feature. Walk the node's 6 per-t edge lists
// concurrently (6 independent chains -> 6x MLP). Same list order as round 5
// -> sums/cnt bit-identical.
__global__ __launch_bounds__(256) void k_sum6(
    const float* __restrict__ feat, const int* __restrict__ src,
    const int* __restrict__ head, const int* __restrict__ nxt,
    float* __restrict__ sums, float* __restrict__ cnt)
{
  const int lane = threadIdx.x & 63;
  const int n = blockIdx.x * (blockDim.x >> 6) + (threadIdx.x >> 6);
  if (n >= N_NODES) return;

  int e0 = head[(size_t)0 * N_NODES + n];
  int e1 = head[(size_t)1 * N_NODES + n];
  int e2 = head[(size_t)2 * N_NODES + n];
  int e3 = head[(size_t)3 * N_NODES + n];
  int e4 = head[(size_t)4 * N_NODES + n];
  int e5 = head[(size_t)5 * N_NODES + n];

  float v0 = 0.f, v1 = 0.f, v2 = 0.f, v3 = 0.f, v4 = 0.f, v5 = 0.f;
  int c0 = 0, c1 = 0, c2 = 0, c3 = 0, c4 = 0, c5 = 0;

  while ((e0 >= 0) | (e1 >= 0) | (e2 >= 0) | (e3 >= 0) | (e4 >= 0) | (e5 >= 0)) {
    if (e0 >= 0) { v0 += feat[(size_t)src[e0] * FDIM + lane]; ++c0; e0 = nxt[e0]; }
    if (e1 >= 0) { v1 += feat[(size_t)src[e1] * FDIM + lane]; ++c1; e1 = nxt[e1]; }
    if (e2 >= 0) { v2 += feat[(size_t)src[e2] * FDIM + lane]; ++c2; e2 = nxt[e2]; }
    if (e3 >= 0) { v3 += feat[(size_t)src[e3] * FDIM + lane]; ++c3; e3 = nxt[e3]; }
    if (e4 >= 0) { v4 += feat[(size_t)src[e4] * FDIM + lane]; ++c4; e4 = nxt[e4]; }
    if (e5 >= 0) { v5 += feat[(size_t)src[e5] * FDIM + lane]; ++c5; e5 = nxt[e5]; }
  }

  sums[((size_t)0 * N_NODES + n) * FDIM + lane] = v0;
  sums[((size_t)1 * N_NODES + n) * FDIM + lane] = v1;
  sums[((size_t)2 * N_NODES + n) * FDIM + lane] = v2;
  sums[((size_t)3 * N_NODES + n) * FDIM + lane] = v3;
  sums[((size_t)4 * N_NODES + n) * FDIM + lane] = v4;
  sums[((size_t)5 * N_NODES + n) * FDIM + lane] = v5;
  if (lane == 0) {
    cnt[(size_t)0 * N_NODES + n] = (float)c0;
    cnt[(size_t)1 * N_NODES + n] = (float)c1;
    cnt[(size_t)2 * N_NODES + n] = (float)c2;
    cnt[(size_t)3 * N_NODES + n] = (float)c3;
    cnt[(size_t)4 * N_NODES + n] = (float)c4;
    cnt[(size_t)5 * N_NODES + n] = (float)c5;
  }
}

// Round-1 arithmetic. Three lessons combined:
//  r7: jb must be blockIdx-derived (block-uniform) -> W stays in batched
//      s_load / SGPR operands.
//  r8: j-slices must be ADJACENT in dispatch order (blockIdx.x % JW), not a
//      separate grid dim -- otherwise each slice re-streams 152MB of sums
//      with no cache reuse (FETCH blew up to 3GB).
//  r6: with only ~1.5-3 waves/SIMD, latency must be hidden by ILP: fully
//      unroll the q loops so the 16 float4 row loads issue back-to-back.
// Unrolling changes scheduling only -- per-iteration expression trees and the
// sequential ss/acc chains are untouched -> rounding identical to round 1.
template <int OUTF, int JBLK>
__global__ __launch_bounds__(64) void k_fused_gemm(
    const float* __restrict__ sums, const float* __restrict__ cnt,
    const float* __restrict__ W, const float* __restrict__ bias,
    float* __restrict__ out)
{
  constexpr int JW = OUTF / JBLK;             // 2 j-slices per node group
  const int lane = threadIdx.x;               // 64-thread block = 1 wave
  const int grp  = blockIdx.x / JW;
  const int jb   = (blockIdx.x % JW) * JBLK;  // block-uniform j-slice

  int n = grp * 64 + lane;
  const bool valid = (n < N_NODES);
  if (!valid) n = N_NODES - 1;

  // ---- pass A: scale factors per t (round-1 arithmetic, q fully unrolled) ----
  float sc0, sc1, sc2, sc3, sc4, sc5;
  #pragma unroll
  for (int t = 0; t < T_STEPS; ++t) {
    const float c  = cnt[(size_t)t * N_NODES + n];
    const float rc = 1.0f / fmaxf(c, 1.0f);
    const float4* row = (const float4*)(sums + ((size_t)t * N_NODES + n) * FDIM);
    float ss = 0.0f;
    #pragma unroll
    for (int q = 0; q < FDIM / 4; ++q) {
      float4 v = row[q];
      float m0 = v.x * rc, m1 = v.y * rc, m2 = v.z * rc, m3 = v.w * rc;
      ss += m0 * m0 + m1 * m1 + m2 * m2 + m3 * m3;
    }
    const float norm = 1.0f - C2 * ss;
    const float s = rc / norm;
    if (t == 0) sc0 = s; else if (t == 1) sc1 = s; else if (t == 2) sc2 = s;
    else if (t == 3) sc3 = s; else if (t == 4) sc4 = s; else sc5 = s;
  }

  // ---- pass B: dense layer, j-slice [jb, jb+JBLK), q8 fully unrolled ----
  float acc[JBLK];
  #pragma unroll
  for (int j = 0; j < JBLK; ++j) acc[j] = bias[jb + j];

  #pragma unroll 1
  for (int t = 0; t < T_STEPS; ++t) {
    const float s = (t == 0) ? sc0 : (t == 1) ? sc1 : (t == 2) ? sc2
                  : (t == 3) ? sc3 : (t == 4) ? sc4 : sc5;
    const float4* row = (const float4*)(sums + ((size_t)t * N_NODES + n) * FDIM);
    #pragma unroll
    for (int q8 = 0; q8 < FDIM / 8; ++q8) {
      const float4 a = row[q8 * 2 + 0];
      const float4 b4 = row[q8 * 2 + 1];
      const float hv[8] = {a.x, a.y, a.z, a.w, b4.x, b4.y, b4.z, b4.w};
      const float* wr = W + ((size_t)t * FDIM + q8 * 8) * OUTF + jb;
      #pragma unroll
      for (int i = 0; i < 8; ++i) {
        const float hs = hv[i] * s;
        #pragma unroll
        for (int j = 0; j < JBLK; ++j)
          acc[j] = fmaf(hs, wr[i * OUTF + j], acc[j]);
      }
    }
  }

  if (valid) {
    float* o = out + (size_t)n * OUTF + jb;
    #pragma unroll
    for (int j = 0; j < JBLK; ++j) o[j] = fmaxf(acc[j], 0.0f);
  }
}

extern "C" void kernel_launch(void* const* d_in, const int* in_sizes, int n_in,
                              void* d_out, int out_size, void* d_ws, size_t ws_size,
                              hipStream_t stream) {
  const float* x  = (const float*)d_in[0];
  const int*  ei  = (const int*)d_in[1];
  const int*  tix = (const int*)d_in[2];
  const float* W1 = (const float*)d_in[3];
  const float* b1 = (const float*)d_in[4];
  const float* W2 = (const float*)d_in[5];
  const float* b2 = (const float*)d_in[6];

  const int* src = ei;
  const int* dst = ei + N_EDGES;

  // Workspace: head[SEG] | nxt[NE] | sums[SEG*64] | cnt[SEG] | h1[NN*64]
  int*   head = (int*)d_ws;
  int*   nxt  = head + SEG;
  float* sums = (float*)(nxt + N_EDGES);
  float* cnt  = sums + (size_t)SEG * FDIM;
  float* h1   = cnt + SEG;

  const int node_grid = (N_NODES + 3) / 4;       // k_sum6: 4 waves/block
  const int ngrp = (N_NODES + 63) / 64;          // 1563 64-node groups
  const int gemm_blocks = ngrp * 2;              // 2 adjacent j-slice blocks/group

  hipMemsetAsync(head, 0xFF, (size_t)SEG * sizeof(int), stream);
  k_build<<<(N_EDGES + 255) / 256, 256, 0, stream>>>(dst, tix, head, nxt);

  // Layer 1
  k_sum6<<<node_grid, 256, 0, stream>>>(x, src, head, nxt, sums, cnt);
  k_fused_gemm<64, 32><<<gemm_blocks, 64, 0, stream>>>(sums, cnt, W1, b1, h1);

  // Layer 2 (same edge lists; cnt identical but rewritten -- harmless)
  k_sum6<<<node_grid, 256, 0, stream>>>(h1, src, head, nxt, sums, cnt);
  k_fused_gemm<16, 8><<<gemm_blocks, 64, 0, stream>>>(sums, cnt, W2, b2, (float*)d_out);
}